// Round 10
// baseline (288.197 us; speedup 1.0000x reference)
//
#include <hip/hip_runtime.h>
#include <hip/hip_bf16.h>

// MultiHeadAttention (single-head, MULTIPLICATIVE tril mask), B=4 T=2048 D=1024.
// Round 6: GEMMs ported to counted-vmcnt pipelined schedule (T3+T4+T5):
//   BM=256 x BN=128 x BK=64, 512 thr (8 waves, 4Mx2N, 64x64/wave),
//   3-buffer LDS rotation (144 KiB), stage tile t+2 during tile t's phases,
//   constant s_waitcnt vmcnt(6) (never 0 in steady state), raw s_barrier,
//   setprio(1) around MFMA clusters. Linear LDS (swizzle deferred).

typedef float  f32x4   __attribute__((ext_vector_type(4)));
typedef __bf16 bf16x8v __attribute__((ext_vector_type(8)));

#define GLOAD_LDS16(g, l) __builtin_amdgcn_global_load_lds(                  \
    (const __attribute__((address_space(1))) void*)(g),                      \
    (__attribute__((address_space(3))) void*)(l), 16, 0, 0)

#define MFMA16(a, b, c) __builtin_amdgcn_mfma_f32_16x16x32_bf16((a), (b), (c), 0, 0, 0)

static constexpr int BB = 4, TT = 2048, DD = 1024;
static constexpr int BM = 256, BN = 128, BK = 64;
static constexpr int NBUF = 3;
static constexpr int ASZ = BM * BK;        // 16384 elems (32 KiB)
static constexpr int BSZ = BN * BK;        // 8192 elems (16 KiB)
static constexpr int BUFSZ = ASZ + BSZ;    // 24576 elems (48 KiB)

// ---------------------------------------------------------------- mainloop
// Pipelined GEMM mainloop. A0: [BM rows][lda], B0 (B^T): [BN rows][ldb].
// Per K-tile: 6 global_load_lds per thread (A:4 units, B:2 units).
// Loop invariant entering tile t: tiles t..t+1 staged/issued; own wave has
// <=12 vmem ops outstanding; vmcnt(6) waits tile t's 6, leaves t+1's 6.
__device__ __forceinline__ void gemm_mainloop_p(
    const __bf16* A0, int lda, const __bf16* B0, int ldb, int K,
    __bf16* lds, f32x4 acc[4][4]) {
  const int tid = threadIdx.x;
  const int lane = tid & 63, w = tid >> 6;
  const int wr = (w >> 1) * 64, wc = (w & 1) * 64;
  const int fr = lane & 15, fq = lane >> 4;
  const int nt = K / BK;

  const int srow = tid >> 3, scol = (tid & 7) * 8;
  const __bf16* ga = A0 + (size_t)srow * lda + scol;
  const __bf16* gb = B0 + (size_t)srow * ldb + scol;
  const int lo = w * 512;  // wave-uniform LDS base (+ lane*16B implicit)

#define STAGE_A(t, i) GLOAD_LDS16(ga + (size_t)((i) * 64) * lda + (t) * BK,   \
                                  lds + ((t) % NBUF) * BUFSZ + (i) * 4096 + lo)
#define STAGE_B(t, i) GLOAD_LDS16(gb + (size_t)((i) * 64) * ldb + (t) * BK,   \
                                  lds + ((t) % NBUF) * BUFSZ + ASZ + (i) * 4096 + lo)

  // prologue: stage tiles 0 and 1 (12 loads in flight per wave)
#pragma unroll
  for (int t = 0; t < 2; ++t) {
    STAGE_A(t, 0); STAGE_A(t, 1); STAGE_A(t, 2); STAGE_A(t, 3);
    STAGE_B(t, 0); STAGE_B(t, 1);
  }

  for (int t = 0; t < nt; ++t) {
    const __bf16* lA = lds + (t % NBUF) * BUFSZ;
    const __bf16* lB = lA + ASZ;
    const bool pf = (t + 2) < nt;

    // wait for tile t's own 6 loads (keep t+1's in flight); then block-wide
    // barrier so ALL waves' staged portions are visible.
    if (t + 1 < nt) asm volatile("s_waitcnt vmcnt(6)" ::: "memory");
    else            asm volatile("s_waitcnt vmcnt(0)" ::: "memory");
    __builtin_amdgcn_s_barrier();

#pragma unroll
    for (int ks = 0; ks < 2; ++ks) {
      bf16x8v bfr[4];
      // ---- phase (ks, half 0): read B row-block + A frags m=0,1
#pragma unroll
      for (int n = 0; n < 4; ++n)
        bfr[n] = *reinterpret_cast<const bf16x8v*>(
            &lB[(wc + n * 16 + fr) * BK + ks * 32 + fq * 8]);
      bf16x8v a0 = *reinterpret_cast<const bf16x8v*>(
          &lA[(wr + 0 * 16 + fr) * BK + ks * 32 + fq * 8]);
      bf16x8v a1 = *reinterpret_cast<const bf16x8v*>(
          &lA[(wr + 1 * 16 + fr) * BK + ks * 32 + fq * 8]);
      if (pf) {
        if (ks == 0) { STAGE_A(t + 2, 0); STAGE_A(t + 2, 1); }
        else         { STAGE_B(t + 2, 0); }
      }
      __builtin_amdgcn_s_barrier();
      __builtin_amdgcn_s_setprio(1);
#pragma unroll
      for (int n = 0; n < 4; ++n) {
        acc[0][n] = MFMA16(a0, bfr[n], acc[0][n]);
        acc[1][n] = MFMA16(a1, bfr[n], acc[1][n]);
      }
      __builtin_amdgcn_s_setprio(0);
      __builtin_amdgcn_s_barrier();

      // ---- phase (ks, half 1): A frags m=2,3 (bfr reused in registers)
      bf16x8v a2 = *reinterpret_cast<const bf16x8v*>(
          &lA[(wr + 2 * 16 + fr) * BK + ks * 32 + fq * 8]);
      bf16x8v a3 = *reinterpret_cast<const bf16x8v*>(
          &lA[(wr + 3 * 16 + fr) * BK + ks * 32 + fq * 8]);
      if (pf) {
        if (ks == 0) { STAGE_A(t + 2, 2); STAGE_A(t + 2, 3); }
        else         { STAGE_B(t + 2, 1); }
      }
      __builtin_amdgcn_s_barrier();
      __builtin_amdgcn_s_setprio(1);
#pragma unroll
      for (int n = 0; n < 4; ++n) {
        acc[2][n] = MFMA16(a2, bfr[n], acc[2][n]);
        acc[3][n] = MFMA16(a3, bfr[n], acc[3][n]);
      }
      __builtin_amdgcn_s_setprio(0);
      __builtin_amdgcn_s_barrier();
    }
  }
#undef STAGE_A
#undef STAGE_B
}

// ---------------------------------------------------------------- kernels
__global__ __launch_bounds__(256) void k_cast_x(const float4* __restrict__ x,
                                                bf16x8v* __restrict__ xb,
                                                int n8) {
  for (int i = blockIdx.x * 256 + threadIdx.x; i < n8; i += gridDim.x * 256) {
    float4 a = x[i * 2], b = x[i * 2 + 1];
    bf16x8v o;
    o[0] = (__bf16)a.x; o[1] = (__bf16)a.y; o[2] = (__bf16)a.z; o[3] = (__bf16)a.w;
    o[4] = (__bf16)b.x; o[5] = (__bf16)b.y; o[6] = (__bf16)b.z; o[7] = (__bf16)b.w;
    xb[i] = o;
  }
}

__global__ __launch_bounds__(1024) void k_transpose_w(
    const float* __restrict__ wq, const float* __restrict__ wk,
    const float* __restrict__ wv, __bf16* __restrict__ wt) {
  __shared__ __bf16 tile[32][33];
  const float* w = (blockIdx.z == 0) ? wq : (blockIdx.z == 1) ? wk : wv;
  const int n0 = blockIdx.x * 32, k0 = blockIdx.y * 32;
  const int tx = threadIdx.x, ty = threadIdx.y;
  tile[ty][tx] = (__bf16)w[(size_t)(k0 + ty) * DD + n0 + tx];
  __syncthreads();
  wt[(size_t)blockIdx.z * DD * DD + (size_t)(n0 + ty) * DD + k0 + tx] =
      tile[tx][ty];
}

__global__ __launch_bounds__(512) void k_gemm_qkv(
    const __bf16* __restrict__ xb, const __bf16* __restrict__ wt,
    __bf16* __restrict__ qb, __bf16* __restrict__ kb,
    __bf16* __restrict__ vt) {
  __shared__ __bf16 lds[NBUF * BUFSZ];
  const int z = blockIdx.z;
  const int row0 = blockIdx.x * BM, col0 = blockIdx.y * BN;
  const __bf16* A0 = xb + (size_t)row0 * DD;
  const __bf16* B0 = wt + (size_t)z * DD * DD + (size_t)col0 * DD;

  f32x4 acc[4][4];
#pragma unroll
  for (int m = 0; m < 4; ++m)
#pragma unroll
    for (int n = 0; n < 4; ++n) acc[m][n] = (f32x4)0.0f;

  gemm_mainloop_p(A0, DD, B0, DD, DD, lds, acc);

  const int tid = threadIdx.x, lane = tid & 63, w = tid >> 6;
  const int wr = (w >> 1) * 64, wc = (w & 1) * 64;
  const int fr = lane & 15, fq = lane >> 4;

  if (z < 2) {
    __bf16* out = z ? kb : qb;
    const float scale = z ? 1.0f : 0.03125f;  // gamma folded into q
#pragma unroll
    for (int m = 0; m < 4; ++m)
#pragma unroll
      for (int n = 0; n < 4; ++n)
#pragma unroll
        for (int i = 0; i < 4; ++i) {
          const int gm = row0 + wr + m * 16 + fq * 4 + i;
          const int gn = col0 + wc + n * 16 + fr;
          out[(size_t)gm * DD + gn] = (__bf16)(acc[m][n][i] * scale);
        }
  } else {
    // vt[b][d][t] = v[b][t][d]
#pragma unroll
    for (int m = 0; m < 4; ++m)
#pragma unroll
      for (int n = 0; n < 4; ++n)
#pragma unroll
        for (int i = 0; i < 4; ++i) {
          const int gm = row0 + wr + m * 16 + fq * 4 + i;  // b*T + t
          const int b = gm >> 11, tl = gm & 2047;
          const int d = col0 + wc + n * 16 + fr;
          vt[((size_t)b * DD + d) * TT + tl] = (__bf16)acc[m][n][i];
        }
  }
}

__global__ __launch_bounds__(512) void k_gemm_scores(
    const __bf16* __restrict__ qb, const __bf16* __restrict__ kb,
    __bf16* __restrict__ Sb) {
  const int row0f = blockIdx.x * BM;          // flattened b*T + t row
  const int b = row0f >> 11;
  const int row0 = row0f & 2047;              // in-batch query row
  const int col0 = blockIdx.y * BN;           // key col
  __bf16* St = Sb + (size_t)b * TT * TT;

  if (col0 > row0 + (BM - 1)) {
    // tile fully above diagonal: multiplicative mask -> exact zeros
    const int4 z4 = {0, 0, 0, 0};
#pragma unroll
    for (int i = 0; i < 8; ++i) {
      const int e = (i * 512 + (int)threadIdx.x) * 8;  // 256*128 elems
      const int r = e >> 7, c = e & 127;
      *reinterpret_cast<int4*>(&St[(size_t)(row0 + r) * TT + col0 + c]) = z4;
    }
    return;
  }

  __shared__ __bf16 lds[NBUF * BUFSZ];
  const __bf16* A0 = qb + ((size_t)b * TT + row0) * DD;
  const __bf16* B0 = kb + ((size_t)b * TT + col0) * DD;

  f32x4 acc[4][4];
#pragma unroll
  for (int m = 0; m < 4; ++m)
#pragma unroll
    for (int n = 0; n < 4; ++n) acc[m][n] = (f32x4)0.0f;

  gemm_mainloop_p(A0, DD, B0, DD, DD, lds, acc);

  const int tid = threadIdx.x, lane = tid & 63, w = tid >> 6;
  const int wr = (w >> 1) * 64, wc = (w & 1) * 64;
  const int fr = lane & 15, fq = lane >> 4;
#pragma unroll
  for (int m = 0; m < 4; ++m)
#pragma unroll
    for (int n = 0; n < 4; ++n)
#pragma unroll
      for (int i = 0; i < 4; ++i) {
        const int gi = row0 + wr + m * 16 + fq * 4 + i;
        const int gj = col0 + wc + n * 16 + fr;
        float v = acc[m][n][i];
        if (gj > gi) v = 0.0f;   // multiplicative mask: exact 0
        St[(size_t)gi * TT + gj] = (__bf16)v;
      }
}

__global__ __launch_bounds__(256) void k_softmax(__bf16* __restrict__ Sb) {
  const int row = blockIdx.x * 4 + (threadIdx.x >> 6);
  const int lane = threadIdx.x & 63;
  __bf16* S = Sb + (size_t)row * TT;

  float v[32];
#pragma unroll
  for (int c = 0; c < 4; ++c) {
    bf16x8v x = *reinterpret_cast<const bf16x8v*>(&S[c * 512 + lane * 8]);
#pragma unroll
    for (int j = 0; j < 8; ++j) v[c * 8 + j] = (float)x[j];
  }
  float m = -1e30f;
#pragma unroll
  for (int i = 0; i < 32; ++i) m = fmaxf(m, v[i]);
#pragma unroll
  for (int off = 32; off >= 1; off >>= 1) m = fmaxf(m, __shfl_xor(m, off));
  float l = 0.0f;
#pragma unroll
  for (int i = 0; i < 32; ++i) {
    v[i] = __expf(v[i] - m);
    l += v[i];
  }
#pragma unroll
  for (int off = 32; off >= 1; off >>= 1) l += __shfl_xor(l, off);
  const float inv = 1.0f / l;
#pragma unroll
  for (int c = 0; c < 4; ++c) {
    bf16x8v o;
#pragma unroll
    for (int j = 0; j < 8; ++j) o[j] = (__bf16)(v[c * 8 + j] * inv);
    *reinterpret_cast<bf16x8v*>(&S[c * 512 + lane * 8]) = o;
  }
}

__global__ __launch_bounds__(512) void k_gemm_pv(
    const __bf16* __restrict__ Sb, const __bf16* __restrict__ vt,
    float* __restrict__ out) {
  __shared__ __bf16 lds[NBUF * BUFSZ];
  const int row0f = blockIdx.x * BM;          // flattened b*T + t row
  const int b = row0f >> 11;
  const int row0 = row0f & 2047;
  const int col0 = blockIdx.y * BN;           // d tile
  const __bf16* A0 = Sb + (size_t)b * TT * TT + (size_t)row0 * TT;
  const __bf16* B0 = vt + (size_t)b * DD * TT + (size_t)col0 * TT;

  f32x4 acc[4][4];
#pragma unroll
  for (int m = 0; m < 4; ++m)
#pragma unroll
    for (int n = 0; n < 4; ++n) acc[m][n] = (f32x4)0.0f;

  gemm_mainloop_p(A0, TT, B0, TT, TT, lds, acc);

  const int tid = threadIdx.x, lane = tid & 63, w = tid >> 6;
  const int wr = (w >> 1) * 64, wc = (w & 1) * 64;
  const int fr = lane & 15, fq = lane >> 4;
#pragma unroll
  for (int m = 0; m < 4; ++m)
#pragma unroll
    for (int n = 0; n < 4; ++n)
#pragma unroll
      for (int i = 0; i < 4; ++i) {
        const int gi = row0 + wr + m * 16 + fq * 4 + i;
        const int gd = col0 + wc + n * 16 + fr;
        out[((size_t)b * TT + gi) * DD + gd] = acc[m][n][i];
      }
}

// ---------------------------------------------------------------- launch
extern "C" void kernel_launch(void* const* d_in, const int* in_sizes, int n_in,
                              void* d_out, int out_size, void* d_ws,
                              size_t ws_size, hipStream_t stream) {
  const float* x  = (const float*)d_in[0];
  const float* wq = (const float*)d_in[1];
  const float* wk = (const float*)d_in[2];
  const float* wv = (const float*)d_in[3];
  float* out = (float*)d_out;

  char* ws = (char*)d_ws;
  __bf16* xb = (__bf16*)ws;                                  // 8192*1024
  __bf16* wt = xb + (size_t)BB * TT * DD;                    // 3*1024*1024
  __bf16* qb = wt + (size_t)3 * DD * DD;                     // 8192*1024
  __bf16* kb = qb + (size_t)BB * TT * DD;
  __bf16* vt = kb + (size_t)BB * TT * DD;                    // [b][d][t]
  __bf16* Sb = vt + (size_t)BB * TT * DD;                    // 4*2048*2048

  k_cast_x<<<2048, 256, 0, stream>>>((const float4*)x, (bf16x8v*)xb,
                                     BB * TT * DD / 8);
  k_transpose_w<<<dim3(32, 32, 3), dim3(32, 32), 0, stream>>>(wq, wk, wv, wt);
  k_gemm_qkv<<<dim3(8192 / BM, 1024 / BN, 3), 512, 0, stream>>>(xb, wt, qb,
                                                                kb, vt);
  k_gemm_scores<<<dim3(8192 / BM, TT / BN), 512, 0, stream>>>(qb, kb, Sb);
  k_softmax<<<2048, 256, 0, stream>>>(Sb);
  k_gemm_pv<<<dim3(8192 / BM, DD / BN), 512, 0, stream>>>(Sb, vt, out);
}

// Round 11
// 239.394 us; speedup vs baseline: 1.2039x; 1.2039x over previous
//
#include <hip/hip_runtime.h>
#include <hip/hip_bf16.h>

// MultiHeadAttention (single-head, MULTIPLICATIVE tril mask), B=4 T=2048 D=1024.
// Round 11: + T2 XOR-swizzle on LDS tiles (rule 21: linear gload_lds dest,
//   pre-swizzled GLOBAL source col, swizzled ds_read col). Fixes the 16-way
//   bank conflict (SQ_LDS_BANK_CONFLICT 1.9e7/dispatch, unchanged r5->r10).
//   Schedule unchanged from r10: BM=256xBN=128xBK=64, 512 thr (8 waves),
//   3-buffer LDS rotation, counted vmcnt(6), raw s_barrier, setprio.

typedef float  f32x4   __attribute__((ext_vector_type(4)));
typedef __bf16 bf16x8v __attribute__((ext_vector_type(8)));

#define GLOAD_LDS16(g, l) __builtin_amdgcn_global_load_lds(                  \
    (const __attribute__((address_space(1))) void*)(g),                      \
    (__attribute__((address_space(3))) void*)(l), 16, 0, 0)

#define MFMA16(a, b, c) __builtin_amdgcn_mfma_f32_16x16x32_bf16((a), (b), (c), 0, 0, 0)

// Swizzled LDS element offset within a [rows][BK] tile: XOR the 16B-slot
// index with (row&7). Spreads the 16 same-slot rows of a fragment read
// across 8 slots -> 2 lanes/bank (free) instead of 16-way conflict.
#define SWZ(row, col) ((row) * BK + ((col) ^ (((row) & 7) << 3)))

static constexpr int BB = 4, TT = 2048, DD = 1024;
static constexpr int BM = 256, BN = 128, BK = 64;
static constexpr int NBUF = 3;
static constexpr int ASZ = BM * BK;        // 16384 elems (32 KiB)
static constexpr int BSZ = BN * BK;        // 8192 elems (16 KiB)
static constexpr int BUFSZ = ASZ + BSZ;    // 24576 elems (48 KiB)

// ---------------------------------------------------------------- mainloop
// Pipelined GEMM mainloop. A0: [BM rows][lda], B0 (B^T): [BN rows][ldb].
// Per K-tile: 6 global_load_lds per thread (A:4 units, B:2 units).
// Loop invariant entering tile t: tiles t..t+1 staged/issued; own wave has
// <=12 vmem ops outstanding; vmcnt(6) waits tile t's 6, leaves t+1's 6.
// LDS dest is LINEAR; global source col is pre-swizzled so that
// LDS[row][s] = G[row][s ^ (row&7)] (16B-slot units); reads use SWZ().
__device__ __forceinline__ void gemm_mainloop_p(
    const __bf16* A0, int lda, const __bf16* B0, int ldb, int K,
    __bf16* lds, f32x4 acc[4][4]) {
  const int tid = threadIdx.x;
  const int lane = tid & 63, w = tid >> 6;
  const int wr = (w >> 1) * 64, wc = (w & 1) * 64;
  const int fr = lane & 15, fq = lane >> 4;
  const int nt = K / BK;

  const int srow = tid >> 3;
  // pre-swizzled source column: slot (tid&7) ^ (srow&7). Stage row offsets
  // are multiples of 64, so (srow + i*64)&7 == srow&7 for all units.
  const int scol = (((tid & 7) ^ (srow & 7)) << 3);
  const __bf16* ga = A0 + (size_t)srow * lda + scol;
  const __bf16* gb = B0 + (size_t)srow * ldb + scol;
  const int lo = w * 512;  // wave-uniform LDS base (+ lane*16B implicit)

#define STAGE_A(t, i) GLOAD_LDS16(ga + (size_t)((i) * 64) * lda + (t) * BK,   \
                                  lds + ((t) % NBUF) * BUFSZ + (i) * 4096 + lo)
#define STAGE_B(t, i) GLOAD_LDS16(gb + (size_t)((i) * 64) * ldb + (t) * BK,   \
                                  lds + ((t) % NBUF) * BUFSZ + ASZ + (i) * 4096 + lo)

  // prologue: stage tiles 0 and 1 (12 loads in flight per wave)
#pragma unroll
  for (int t = 0; t < 2; ++t) {
    STAGE_A(t, 0); STAGE_A(t, 1); STAGE_A(t, 2); STAGE_A(t, 3);
    STAGE_B(t, 0); STAGE_B(t, 1);
  }

  for (int t = 0; t < nt; ++t) {
    const __bf16* lA = lds + (t % NBUF) * BUFSZ;
    const __bf16* lB = lA + ASZ;
    const bool pf = (t + 2) < nt;

    // wait for tile t's own 6 loads (keep t+1's in flight); then block-wide
    // barrier so ALL waves' staged portions are visible.
    if (t + 1 < nt) asm volatile("s_waitcnt vmcnt(6)" ::: "memory");
    else            asm volatile("s_waitcnt vmcnt(0)" ::: "memory");
    __builtin_amdgcn_s_barrier();

#pragma unroll
    for (int ks = 0; ks < 2; ++ks) {
      bf16x8v bfr[4];
      // ---- phase (ks, half 0): read B row-block + A frags m=0,1
#pragma unroll
      for (int n = 0; n < 4; ++n)
        bfr[n] = *reinterpret_cast<const bf16x8v*>(
            &lB[SWZ(wc + n * 16 + fr, ks * 32 + fq * 8)]);
      bf16x8v a0 = *reinterpret_cast<const bf16x8v*>(
          &lA[SWZ(wr + 0 * 16 + fr, ks * 32 + fq * 8)]);
      bf16x8v a1 = *reinterpret_cast<const bf16x8v*>(
          &lA[SWZ(wr + 1 * 16 + fr, ks * 32 + fq * 8)]);
      if (pf) {
        if (ks == 0) { STAGE_A(t + 2, 0); STAGE_A(t + 2, 1); }
        else         { STAGE_B(t + 2, 0); }
      }
      __builtin_amdgcn_s_barrier();
      __builtin_amdgcn_s_setprio(1);
#pragma unroll
      for (int n = 0; n < 4; ++n) {
        acc[0][n] = MFMA16(a0, bfr[n], acc[0][n]);
        acc[1][n] = MFMA16(a1, bfr[n], acc[1][n]);
      }
      __builtin_amdgcn_s_setprio(0);
      __builtin_amdgcn_s_barrier();

      // ---- phase (ks, half 1): A frags m=2,3 (bfr reused in registers)
      bf16x8v a2 = *reinterpret_cast<const bf16x8v*>(
          &lA[SWZ(wr + 2 * 16 + fr, ks * 32 + fq * 8)]);
      bf16x8v a3 = *reinterpret_cast<const bf16x8v*>(
          &lA[SWZ(wr + 3 * 16 + fr, ks * 32 + fq * 8)]);
      if (pf) {
        if (ks == 0) { STAGE_A(t + 2, 2); STAGE_A(t + 2, 3); }
        else         { STAGE_B(t + 2, 1); }
      }
      __builtin_amdgcn_s_barrier();
      __builtin_amdgcn_s_setprio(1);
#pragma unroll
      for (int n = 0; n < 4; ++n) {
        acc[2][n] = MFMA16(a2, bfr[n], acc[2][n]);
        acc[3][n] = MFMA16(a3, bfr[n], acc[3][n]);
      }
      __builtin_amdgcn_s_setprio(0);
      __builtin_amdgcn_s_barrier();
    }
  }
#undef STAGE_A
#undef STAGE_B
}

// ---------------------------------------------------------------- kernels
__global__ __launch_bounds__(256) void k_cast_x(const float4* __restrict__ x,
                                                bf16x8v* __restrict__ xb,
                                                int n8) {
  for (int i = blockIdx.x * 256 + threadIdx.x; i < n8; i += gridDim.x * 256) {
    float4 a = x[i * 2], b = x[i * 2 + 1];
    bf16x8v o;
    o[0] = (__bf16)a.x; o[1] = (__bf16)a.y; o[2] = (__bf16)a.z; o[3] = (__bf16)a.w;
    o[4] = (__bf16)b.x; o[5] = (__bf16)b.y; o[6] = (__bf16)b.z; o[7] = (__bf16)b.w;
    xb[i] = o;
  }
}

__global__ __launch_bounds__(1024) void k_transpose_w(
    const float* __restrict__ wq, const float* __restrict__ wk,
    const float* __restrict__ wv, __bf16* __restrict__ wt) {
  __shared__ __bf16 tile[32][33];
  const float* w = (blockIdx.z == 0) ? wq : (blockIdx.z == 1) ? wk : wv;
  const int n0 = blockIdx.x * 32, k0 = blockIdx.y * 32;
  const int tx = threadIdx.x, ty = threadIdx.y;
  tile[ty][tx] = (__bf16)w[(size_t)(k0 + ty) * DD + n0 + tx];
  __syncthreads();
  wt[(size_t)blockIdx.z * DD * DD + (size_t)(n0 + ty) * DD + k0 + tx] =
      tile[tx][ty];
}

__global__ __launch_bounds__(512) void k_gemm_qkv(
    const __bf16* __restrict__ xb, const __bf16* __restrict__ wt,
    __bf16* __restrict__ qb, __bf16* __restrict__ kb,
    __bf16* __restrict__ vt) {
  __shared__ __bf16 lds[NBUF * BUFSZ];
  const int z = blockIdx.z;
  const int row0 = blockIdx.x * BM, col0 = blockIdx.y * BN;
  const __bf16* A0 = xb + (size_t)row0 * DD;
  const __bf16* B0 = wt + (size_t)z * DD * DD + (size_t)col0 * DD;

  f32x4 acc[4][4];
#pragma unroll
  for (int m = 0; m < 4; ++m)
#pragma unroll
    for (int n = 0; n < 4; ++n) acc[m][n] = (f32x4)0.0f;

  gemm_mainloop_p(A0, DD, B0, DD, DD, lds, acc);

  const int tid = threadIdx.x, lane = tid & 63, w = tid >> 6;
  const int wr = (w >> 1) * 64, wc = (w & 1) * 64;
  const int fr = lane & 15, fq = lane >> 4;

  if (z < 2) {
    __bf16* out = z ? kb : qb;
    const float scale = z ? 1.0f : 0.03125f;  // gamma folded into q
#pragma unroll
    for (int m = 0; m < 4; ++m)
#pragma unroll
      for (int n = 0; n < 4; ++n)
#pragma unroll
        for (int i = 0; i < 4; ++i) {
          const int gm = row0 + wr + m * 16 + fq * 4 + i;
          const int gn = col0 + wc + n * 16 + fr;
          out[(size_t)gm * DD + gn] = (__bf16)(acc[m][n][i] * scale);
        }
  } else {
    // vt[b][d][t] = v[b][t][d]
#pragma unroll
    for (int m = 0; m < 4; ++m)
#pragma unroll
      for (int n = 0; n < 4; ++n)
#pragma unroll
        for (int i = 0; i < 4; ++i) {
          const int gm = row0 + wr + m * 16 + fq * 4 + i;  // b*T + t
          const int b = gm >> 11, tl = gm & 2047;
          const int d = col0 + wc + n * 16 + fr;
          vt[((size_t)b * DD + d) * TT + tl] = (__bf16)acc[m][n][i];
        }
  }
}

__global__ __launch_bounds__(512) void k_gemm_scores(
    const __bf16* __restrict__ qb, const __bf16* __restrict__ kb,
    __bf16* __restrict__ Sb) {
  const int row0f = blockIdx.x * BM;          // flattened b*T + t row
  const int b = row0f >> 11;
  const int row0 = row0f & 2047;              // in-batch query row
  const int col0 = blockIdx.y * BN;           // key col
  __bf16* St = Sb + (size_t)b * TT * TT;

  if (col0 > row0 + (BM - 1)) {
    // tile fully above diagonal: multiplicative mask -> exact zeros
    const int4 z4 = {0, 0, 0, 0};
#pragma unroll
    for (int i = 0; i < 8; ++i) {
      const int e = (i * 512 + (int)threadIdx.x) * 8;  // 256*128 elems
      const int r = e >> 7, c = e & 127;
      *reinterpret_cast<int4*>(&St[(size_t)(row0 + r) * TT + col0 + c]) = z4;
    }
    return;
  }

  __shared__ __bf16 lds[NBUF * BUFSZ];
  const __bf16* A0 = qb + ((size_t)b * TT + row0) * DD;
  const __bf16* B0 = kb + ((size_t)b * TT + col0) * DD;

  f32x4 acc[4][4];
#pragma unroll
  for (int m = 0; m < 4; ++m)
#pragma unroll
    for (int n = 0; n < 4; ++n) acc[m][n] = (f32x4)0.0f;

  gemm_mainloop_p(A0, DD, B0, DD, DD, lds, acc);

  const int tid = threadIdx.x, lane = tid & 63, w = tid >> 6;
  const int wr = (w >> 1) * 64, wc = (w & 1) * 64;
  const int fr = lane & 15, fq = lane >> 4;
#pragma unroll
  for (int m = 0; m < 4; ++m)
#pragma unroll
    for (int n = 0; n < 4; ++n)
#pragma unroll
      for (int i = 0; i < 4; ++i) {
        const int gi = row0 + wr + m * 16 + fq * 4 + i;
        const int gj = col0 + wc + n * 16 + fr;
        float v = acc[m][n][i];
        if (gj > gi) v = 0.0f;   // multiplicative mask: exact 0
        St[(size_t)gi * TT + gj] = (__bf16)v;
      }
}

__global__ __launch_bounds__(256) void k_softmax(__bf16* __restrict__ Sb) {
  const int row = blockIdx.x * 4 + (threadIdx.x >> 6);
  const int lane = threadIdx.x & 63;
  __bf16* S = Sb + (size_t)row * TT;

  float v[32];
#pragma unroll
  for (int c = 0; c < 4; ++c) {
    bf16x8v x = *reinterpret_cast<const bf16x8v*>(&S[c * 512 + lane * 8]);
#pragma unroll
    for (int j = 0; j < 8; ++j) v[c * 8 + j] = (float)x[j];
  }
  float m = -1e30f;
#pragma unroll
  for (int i = 0; i < 32; ++i) m = fmaxf(m, v[i]);
#pragma unroll
  for (int off = 32; off >= 1; off >>= 1) m = fmaxf(m, __shfl_xor(m, off));
  float l = 0.0f;
#pragma unroll
  for (int i = 0; i < 32; ++i) {
    v[i] = __expf(v[i] - m);
    l += v[i];
  }
#pragma unroll
  for (int off = 32; off >= 1; off >>= 1) l += __shfl_xor(l, off);
  const float inv = 1.0f / l;
#pragma unroll
  for (int c = 0; c < 4; ++c) {
    bf16x8v o;
#pragma unroll
    for (int j = 0; j < 8; ++j) o[j] = (__bf16)(v[c * 8 + j] * inv);
    *reinterpret_cast<bf16x8v*>(&S[c * 512 + lane * 8]) = o;
  }
}

__global__ __launch_bounds__(512) void k_gemm_pv(
    const __bf16* __restrict__ Sb, const __bf16* __restrict__ vt,
    float* __restrict__ out) {
  __shared__ __bf16 lds[NBUF * BUFSZ];
  const int row0f = blockIdx.x * BM;          // flattened b*T + t row
  const int b = row0f >> 11;
  const int row0 = row0f & 2047;
  const int col0 = blockIdx.y * BN;           // d tile
  const __bf16* A0 = Sb + (size_t)b * TT * TT + (size_t)row0 * TT;
  const __bf16* B0 = vt + (size_t)b * DD * TT + (size_t)col0 * TT;

  f32x4 acc[4][4];
#pragma unroll
  for (int m = 0; m < 4; ++m)
#pragma unroll
    for (int n = 0; n < 4; ++n) acc[m][n] = (f32x4)0.0f;

  gemm_mainloop_p(A0, TT, B0, TT, TT, lds, acc);

  const int tid = threadIdx.x, lane = tid & 63, w = tid >> 6;
  const int wr = (w >> 1) * 64, wc = (w & 1) * 64;
  const int fr = lane & 15, fq = lane >> 4;
#pragma unroll
  for (int m = 0; m < 4; ++m)
#pragma unroll
    for (int n = 0; n < 4; ++n)
#pragma unroll
      for (int i = 0; i < 4; ++i) {
        const int gi = row0 + wr + m * 16 + fq * 4 + i;
        const int gd = col0 + wc + n * 16 + fr;
        out[((size_t)b * TT + gi) * DD + gd] = acc[m][n][i];
      }
}

// ---------------------------------------------------------------- launch
extern "C" void kernel_launch(void* const* d_in, const int* in_sizes, int n_in,
                              void* d_out, int out_size, void* d_ws,
                              size_t ws_size, hipStream_t stream) {
  const float* x  = (const float*)d_in[0];
  const float* wq = (const float*)d_in[1];
  const float* wk = (const float*)d_in[2];
  const float* wv = (const float*)d_in[3];
  float* out = (float*)d_out;

  char* ws = (char*)d_ws;
  __bf16* xb = (__bf16*)ws;                                  // 8192*1024
  __bf16* wt = xb + (size_t)BB * TT * DD;                    // 3*1024*1024
  __bf16* qb = wt + (size_t)3 * DD * DD;                     // 8192*1024
  __bf16* kb = qb + (size_t)BB * TT * DD;
  __bf16* vt = kb + (size_t)BB * TT * DD;                    // [b][d][t]
  __bf16* Sb = vt + (size_t)BB * TT * DD;                    // 4*2048*2048

  k_cast_x<<<2048, 256, 0, stream>>>((const float4*)x, (bf16x8v*)xb,
                                     BB * TT * DD / 8);
  k_transpose_w<<<dim3(32, 32, 3), dim3(32, 32), 0, stream>>>(wq, wk, wv, wt);
  k_gemm_qkv<<<dim3(8192 / BM, 1024 / BN, 3), 512, 0, stream>>>(xb, wt, qb,
                                                                kb, vt);
  k_gemm_scores<<<dim3(8192 / BM, TT / BN), 512, 0, stream>>>(qb, kb, Sb);
  k_softmax<<<2048, 256, 0, stream>>>(Sb);
  k_gemm_pv<<<dim3(8192 / BM, DD / BN), 512, 0, stream>>>(Sb, vt, out);
}